// Round 1
// baseline (854.866 us; speedup 1.0000x reference)
//
#include <hip/hip_runtime.h>
#include <cstddef>

#define D 128
#define GR 128  // rows per GEMM block

__global__ void k_deg_init(int* __restrict__ deg, int n) {
  int i = blockIdx.x * blockDim.x + threadIdx.x;
  if (i < n) deg[i] = 1;  // self-loop
}

__global__ void k_deg_count(const int* __restrict__ dst, int e, int* __restrict__ deg) {
  int i = blockIdx.x * blockDim.x + threadIdx.x;
  if (i < e) atomicAdd(&deg[dst[i]], 1);
}

__global__ void k_dinv(const int* __restrict__ deg, float* __restrict__ dinv, int n) {
  int i = blockIdx.x * blockDim.x + threadIdx.x;
  if (i < n) {
    float d = (float)deg[i];
    float v = 1.0f / sqrtf(d);
    dinv[i] = fminf(v, 1.0e6f);
  }
}

// h = x @ W^T + b ; out = h * dinv^2 (self-loop contribution, initializes out)
__global__ __launch_bounds__(256) void k_gemm(
    const float* __restrict__ x, const float* __restrict__ W,
    const float* __restrict__ bias, const float* __restrict__ dinv,
    float* __restrict__ h, float* __restrict__ out, int n) {
  __shared__ float Ws[128 * 132];
  __shared__ float xs[GR * 132];
  const int tid = threadIdx.x;

  // Load W[j][k] -> Ws[j*132+k] (pad stride 132 keeps 16B alignment, spreads banks)
  for (int i = tid; i < 128 * 32; i += 256) {
    const int row = i >> 5, c4 = (i & 31) << 2;
    const float4 w = reinterpret_cast<const float4*>(W)[i];
    float* p = &Ws[row * 132 + c4];
    p[0] = w.x; p[1] = w.y; p[2] = w.z; p[3] = w.w;
  }
  const int row0 = blockIdx.x * GR;
  for (int i = tid; i < GR * 32; i += 256) {
    const int r = i >> 5, c4 = (i & 31) << 2;
    float4 v = make_float4(0.f, 0.f, 0.f, 0.f);
    if (row0 + r < n)
      v = reinterpret_cast<const float4*>(x + (size_t)(row0 + r) * D)[i & 31];
    float* p = &xs[r * 132 + c4];
    p[0] = v.x; p[1] = v.y; p[2] = v.z; p[3] = v.w;
  }
  __syncthreads();

  const int jc = tid & 15;  // cols: jc + 16*dj
  const int rg = tid >> 4;  // rows: rg + 16*i  (stride-16 so the 4 rg's per wave hit 4 distinct bank quads)
  float acc[8][8];
#pragma unroll
  for (int i = 0; i < 8; ++i)
#pragma unroll
    for (int dj = 0; dj < 8; ++dj) acc[i][dj] = 0.f;

  for (int k = 0; k < 128; k += 4) {
    float4 wv[8];
#pragma unroll
    for (int dj = 0; dj < 8; ++dj)
      wv[dj] = *reinterpret_cast<const float4*>(&Ws[(jc + 16 * dj) * 132 + k]);
#pragma unroll
    for (int i = 0; i < 8; ++i) {
      const float4 xv = *reinterpret_cast<const float4*>(&xs[(rg + 16 * i) * 132 + k]);
#pragma unroll
      for (int dj = 0; dj < 8; ++dj) {
        acc[i][dj] += xv.x * wv[dj].x;
        acc[i][dj] += xv.y * wv[dj].y;
        acc[i][dj] += xv.z * wv[dj].z;
        acc[i][dj] += xv.w * wv[dj].w;
      }
    }
  }

#pragma unroll
  for (int i = 0; i < 8; ++i) {
    const int r = row0 + rg + 16 * i;
    if (r < n) {
      const float di = dinv[r];
      const float s = di * di;
#pragma unroll
      for (int dj = 0; dj < 8; ++dj) {
        const int j = jc + 16 * dj;
        const float v = acc[i][dj] + bias[j];
        h[(size_t)r * D + j] = v;
        out[(size_t)r * D + j] = v * s;  // self-loop term; also initializes out
      }
    }
  }
}

// per edge: out[dst] += h[src] * dinv[src]*dinv[dst]; 128 lanes per edge, 2 edges/block
__global__ __launch_bounds__(256) void k_scatter(
    const int* __restrict__ src, const int* __restrict__ dst,
    const float* __restrict__ dinv, const float* __restrict__ h,
    float* __restrict__ out, int e) {
  const int j = threadIdx.x & 127;
  const long eidx = (long)blockIdx.x * 2 + (threadIdx.x >> 7);
  if (eidx < e) {
    const int s = src[eidx];
    const int d = dst[eidx];
    const float nrm = dinv[s] * dinv[d];
    atomicAdd(&out[(size_t)d * D + j], h[(size_t)s * D + j] * nrm);
  }
}

extern "C" void kernel_launch(void* const* d_in, const int* in_sizes, int n_in,
                              void* d_out, int out_size, void* d_ws, size_t ws_size,
                              hipStream_t stream) {
  const float* x = (const float*)d_in[0];
  const int* ei = (const int*)d_in[1];
  const float* W = (const float*)d_in[2];
  const float* b = (const float*)d_in[3];
  float* out = (float*)d_out;
  const int n = in_sizes[0] / D;
  const int e = in_sizes[1] / 2;
  const int* src = ei;       // edge_index[0]
  const int* dst = ei + e;   // edge_index[1]

  char* ws = (char*)d_ws;
  const size_t nb = ((size_t)n * 4 + 255) / 256 * 256;
  int* deg = (int*)ws;
  float* dinv = (float*)(ws + nb);
  float* h = (float*)(ws + 2 * nb);

  k_deg_init<<<(n + 255) / 256, 256, 0, stream>>>(deg, n);
  k_deg_count<<<(e + 255) / 256, 256, 0, stream>>>(dst, e, deg);
  k_dinv<<<(n + 255) / 256, 256, 0, stream>>>(deg, dinv, n);
  k_gemm<<<(n + GR - 1) / GR, 256, 0, stream>>>(x, W, b, dinv, h, out, n);
  k_scatter<<<(e + 1) / 2, 256, 0, stream>>>(src, dst, dinv, h, out, e);
}

// Round 3
// 388.506 us; speedup vs baseline: 2.2004x; 2.2004x over previous
//
#include <hip/hip_runtime.h>
#include <cstddef>

#define D 128
#define GR 128  // rows per GEMM block

__global__ void k_zero(int* __restrict__ p, int n) {
  int i = blockIdx.x * blockDim.x + threadIdx.x;
  if (i < n) p[i] = 0;
}

__global__ void k_deg_count(const int* __restrict__ dst, int e, int* __restrict__ cnt) {
  int i = blockIdx.x * blockDim.x + threadIdx.x;
  if (i < e) atomicAdd(&cnt[dst[i]], 1);
}

// dinv = min((cnt+1)^-0.5, 1e6)  (cnt excludes self-loop; deg = cnt+1)
__global__ void k_dinv(const int* __restrict__ cnt, float* __restrict__ dinv, int n) {
  int i = blockIdx.x * blockDim.x + threadIdx.x;
  if (i < n) {
    float d = (float)(cnt[i] + 1);
    dinv[i] = fminf(rsqrtf(d), 1.0e6f);
  }
}

// ---- exclusive scan of cnt[0..n) -> rowptr, 1024 elems/block ----
__global__ __launch_bounds__(256) void k_scan1(const int* __restrict__ cnt,
                                               int* __restrict__ rowptr,
                                               int* __restrict__ bsums, int n) {
  __shared__ int sdata[256];
  const int tid = threadIdx.x;
  const int idx = blockIdx.x * 1024 + tid * 4;
  int v[4], s = 0;
#pragma unroll
  for (int u = 0; u < 4; ++u) {
    int c = (idx + u < n) ? cnt[idx + u] : 0;
    v[u] = s; s += c;
  }
  sdata[tid] = s;
  __syncthreads();
  for (int off = 1; off < 256; off <<= 1) {
    int t = (tid >= off) ? sdata[tid - off] : 0;
    __syncthreads();
    sdata[tid] += t;
    __syncthreads();
  }
  const int excl = (tid > 0) ? sdata[tid - 1] : 0;
#pragma unroll
  for (int u = 0; u < 4; ++u)
    if (idx + u < n) rowptr[idx + u] = excl + v[u];
  if (tid == 255) bsums[blockIdx.x] = sdata[255];
}

__global__ __launch_bounds__(256) void k_scan2(int* __restrict__ bsums, int nb) {
  __shared__ int sdata[256];
  const int tid = threadIdx.x;
  sdata[tid] = (tid < nb) ? bsums[tid] : 0;
  __syncthreads();
  for (int off = 1; off < 256; off <<= 1) {
    int t = (tid >= off) ? sdata[tid - off] : 0;
    __syncthreads();
    sdata[tid] += t;
    __syncthreads();
  }
  const int excl = (tid > 0) ? sdata[tid - 1] : 0;
  if (tid < nb) bsums[tid] = excl;
}

__global__ void k_scan3(int* __restrict__ rowptr, const int* __restrict__ bsums, int n) {
  int i = blockIdx.x * blockDim.x + threadIdx.x;
  if (i < n) rowptr[i] += bsums[i >> 10];
}

// srcs[rowptr[d] + cursor[d]++] = s   (cursor ends up == in-degree again)
__global__ void k_fill(const int* __restrict__ src, const int* __restrict__ dst,
                       const int* __restrict__ rowptr, int* __restrict__ cursor,
                       int* __restrict__ srcs, int e) {
  int i = blockIdx.x * blockDim.x + threadIdx.x;
  if (i < e) {
    const int d = dst[i];
    const int pos = rowptr[d] + atomicAdd(&cursor[d], 1);
    srcs[pos] = src[i];
  }
}

// g = (x @ W^T + b) * dinv[r]
__global__ __launch_bounds__(256) void k_gemm(
    const float* __restrict__ x, const float* __restrict__ W,
    const float* __restrict__ bias, const float* __restrict__ dinv,
    float* __restrict__ g, int n) {
  __shared__ float Ws[128 * 132];
  __shared__ float xs[GR * 132];
  const int tid = threadIdx.x;

  for (int i = tid; i < 128 * 32; i += 256) {
    const int row = i >> 5, c4 = (i & 31) << 2;
    const float4 w = reinterpret_cast<const float4*>(W)[i];
    float* p = &Ws[row * 132 + c4];
    p[0] = w.x; p[1] = w.y; p[2] = w.z; p[3] = w.w;
  }
  const int row0 = blockIdx.x * GR;
  for (int i = tid; i < GR * 32; i += 256) {
    const int r = i >> 5, c4 = (i & 31) << 2;
    float4 v = make_float4(0.f, 0.f, 0.f, 0.f);
    if (row0 + r < n)
      v = reinterpret_cast<const float4*>(x + (size_t)(row0 + r) * D)[i & 31];
    float* p = &xs[r * 132 + c4];
    p[0] = v.x; p[1] = v.y; p[2] = v.z; p[3] = v.w;
  }
  __syncthreads();

  const int jc = tid & 15;
  const int rg = tid >> 4;
  float acc[8][8];
#pragma unroll
  for (int i = 0; i < 8; ++i)
#pragma unroll
    for (int dj = 0; dj < 8; ++dj) acc[i][dj] = 0.f;

  for (int k = 0; k < 128; k += 4) {
    float4 wv[8];
#pragma unroll
    for (int dj = 0; dj < 8; ++dj)
      wv[dj] = *reinterpret_cast<const float4*>(&Ws[(jc + 16 * dj) * 132 + k]);
#pragma unroll
    for (int i = 0; i < 8; ++i) {
      const float4 xv = *reinterpret_cast<const float4*>(&xs[(rg + 16 * i) * 132 + k]);
#pragma unroll
      for (int dj = 0; dj < 8; ++dj) {
        acc[i][dj] += xv.x * wv[dj].x;
        acc[i][dj] += xv.y * wv[dj].y;
        acc[i][dj] += xv.z * wv[dj].z;
        acc[i][dj] += xv.w * wv[dj].w;
      }
    }
  }

#pragma unroll
  for (int i = 0; i < 8; ++i) {
    const int r = row0 + rg + 16 * i;
    if (r < n) {
      const float s = dinv[r];
#pragma unroll
      for (int dj = 0; dj < 8; ++dj) {
        const int j = jc + 16 * dj;
        g[(size_t)r * D + j] = (acc[i][dj] + bias[j]) * s;
      }
    }
  }
}

// one wave per node: out[v] = dinv[v] * (g[v] + sum_{s in in(v)} g[s])
__global__ __launch_bounds__(256) void k_accum(
    const int* __restrict__ rowptr, const int* __restrict__ cnt,
    const int* __restrict__ srcs, const float* __restrict__ g,
    const float* __restrict__ dinv, float* __restrict__ out, int n) {
  const int w = (int)(((size_t)blockIdx.x * 256 + threadIdx.x) >> 6);  // wave id = node
  const int lane = threadIdx.x & 63;
  if (w >= n) return;
  const int beg = rowptr[w];
  const int num = cnt[w];
  const float2* __restrict__ gp = (const float2*)g;
  float2 a = gp[(size_t)w * 64 + lane];  // self-loop term (g already dinv-scaled)
  int k = 0;
  for (; k + 8 <= num; k += 8) {
    float2 t[8];
#pragma unroll
    for (int u = 0; u < 8; ++u) {
      const int s = srcs[beg + k + u];
      t[u] = gp[(size_t)s * 64 + lane];
    }
#pragma unroll
    for (int u = 0; u < 8; ++u) { a.x += t[u].x; a.y += t[u].y; }
  }
  for (; k < num; ++k) {
    const int s = srcs[beg + k];
    const float2 t = gp[(size_t)s * 64 + lane];
    a.x += t.x; a.y += t.y;
  }
  const float dv = dinv[w];
  ((float2*)out)[(size_t)w * 64 + lane] = make_float2(a.x * dv, a.y * dv);
}

extern "C" void kernel_launch(void* const* d_in, const int* in_sizes, int n_in,
                              void* d_out, int out_size, void* d_ws, size_t ws_size,
                              hipStream_t stream) {
  const float* x = (const float*)d_in[0];
  const int* ei = (const int*)d_in[1];
  const float* W = (const float*)d_in[2];
  const float* b = (const float*)d_in[3];
  float* out = (float*)d_out;
  const int n = in_sizes[0] / D;
  const int e = in_sizes[1] / 2;
  const int* src = ei;      // edge_index[0]
  const int* dst = ei + e;  // edge_index[1]

  char* ws = (char*)d_ws;
  const size_t nb = ((size_t)n * 4 + 255) / 256 * 256;
  int* rowptr = (int*)ws;                    // n ints
  int* cnt = (int*)(ws + nb);                // n ints (deg count, then cursor)
  float* dinv = (float*)(ws + 2 * nb);       // n floats
  int* bsums = (int*)(ws + 3 * nb);          // <=512 ints
  int* srcs = (int*)(ws + 3 * nb + 4096);    // e ints
  const size_t eb = ((size_t)e * 4 + 255) / 256 * 256;
  float* g = (float*)(ws + 3 * nb + 4096 + eb);  // n*128 floats

  const int nscan = (n + 1023) / 1024;

  k_zero<<<(n + 255) / 256, 256, 0, stream>>>(cnt, n);
  k_deg_count<<<(e + 255) / 256, 256, 0, stream>>>(dst, e, cnt);
  k_dinv<<<(n + 255) / 256, 256, 0, stream>>>(cnt, dinv, n);
  k_scan1<<<nscan, 256, 0, stream>>>(cnt, rowptr, bsums, n);
  k_scan2<<<1, 256, 0, stream>>>(bsums, nscan);
  k_scan3<<<(n + 255) / 256, 256, 0, stream>>>(rowptr, bsums, n);
  k_zero<<<(n + 255) / 256, 256, 0, stream>>>(cnt, n);  // cnt -> cursor
  k_gemm<<<(n + GR - 1) / GR, 256, 0, stream>>>(x, W, b, dinv, g, n);
  k_fill<<<(e + 255) / 256, 256, 0, stream>>>(src, dst, rowptr, cnt, srcs, e);
  // one 64-lane wave per node -> n waves -> n/4 blocks of 256 threads
  k_accum<<<(n + 3) / 4, 256, 0, stream>>>(rowptr, cnt, srcs, g, dinv, out, n);
}